// Round 2
// baseline (6171.972 us; speedup 1.0000x reference)
//
#include <hip/hip_runtime.h>

#define TT 2048
#define HD 64
#define RB 4          // rows (batch) per block

__device__ __forceinline__ float fsig(float x)  { return 1.0f / (1.0f + __expf(-x)); }
__device__ __forceinline__ float ftanh_(float x){ return 1.0f - 2.0f / (1.0f + __expf(2.0f * x)); }

// Block = 768 threads:
//   threads [0,256):   layer0. j = t>>2 (unit), ck = t&3  (K chunk of 16 over K=64)
//   threads [256,768): layer1. j = p>>3 (unit), ck = p&7  (K chunk of 16 over K=128 = [h1|h2])
// Chunk-threads of a unit sit in adjacent lanes -> shfl_xor butterfly combines partials.
// Pipeline: iteration i computes layer0 step i and layer1 step i-1; ONE barrier/step.
__global__ __launch_bounds__(768, 3)
void lstm2_kernel(const float* __restrict__ x,
                  const float* __restrict__ Wih0,
                  const float* __restrict__ Whh0,
                  const float* __restrict__ bih0,
                  const float* __restrict__ bhh0,
                  const float* __restrict__ Wih1,
                  const float* __restrict__ Whh1,
                  const float* __restrict__ bih1,
                  const float* __restrict__ bhh1,
                  const float* __restrict__ fcW,
                  const float* __restrict__ fcb,
                  float* __restrict__ out)
{
    const int tid  = threadIdx.x;
    const int blk  = blockIdx.x;
    const int row0 = blk * RB;

    __shared__ float h0buf[2][RB][HD];   // h0[t] in h0buf[t&1]
    __shared__ float h2buf[2][RB][HD];   // h2[t] in h2buf[t&1]
    __shared__ float fcs[RB * HD];

    const bool isL0 = (tid < 256);
    const int  p    = isL0 ? tid : (tid - 256);
    const int  j    = isL0 ? (p >> 2) : (p >> 3);   // hidden unit
    const int  ck   = isL0 ? (p & 3)  : (p & 7);    // k-chunk index

    // ---------------- weights: 4 gates x 16 K -> 64 VGPRs ----------------
    float w[4][16];
    float bg[4];   // bias per gate (added by ck==0 only)
    float wx[4];   // layer0: Wih0 per gate
    {
        const float* Wsrc;
        int kbase;
        if (isL0)        { Wsrc = Whh0; kbase = 16 * ck; }
        else if (ck < 4) { Wsrc = Wih1; kbase = 16 * ck; }
        else             { Wsrc = Whh1; kbase = 16 * ck - HD; }
        #pragma unroll
        for (int g = 0; g < 4; ++g) {
            const int gr = g * HD + j;
            const float4* W = (const float4*)(Wsrc + gr * HD + kbase);
            #pragma unroll
            for (int k4 = 0; k4 < 4; ++k4) {
                const float4 v = W[k4];
                w[g][4*k4+0] = v.x; w[g][4*k4+1] = v.y;
                w[g][4*k4+2] = v.z; w[g][4*k4+3] = v.w;
            }
            if (isL0) { bg[g] = bih0[gr] + bhh0[gr]; wx[g] = Wih0[gr]; }
            else      { bg[g] = bih1[gr] + bhh1[gr]; wx[g] = 0.0f;    }
        }
    }

    // zero both parities of both h buffers
    for (int z = tid; z < 2 * RB * HD; z += 768) ((float*)h0buf)[z] = 0.0f;
    for (int z = tid; z < 2 * RB * HD; z += 768) ((float*)h2buf)[z] = 0.0f;

    float cc = 0.0f, hlast = 0.0f;
    const float fcwj = (!isL0 && ck < 4) ? fcW[j] : 0.0f;

    float xv[RB], xn[RB];
    if (isL0) {
        #pragma unroll
        for (int r = 0; r < RB; ++r) xn[r] = x[(row0 + r) * TT];
    }
    __syncthreads();

    for (int i = 0; i <= TT; ++i) {
        const int pr = (i + 1) & 1;   // h0[i-1] lives here; layer1 writes h2[i-1] here
        const int pw = i & 1;         // layer0 writes h0[i] here; h2[i-2] lives here
        float acc[RB][4];

        if (isL0) {
            // -------- layer0, step i --------
            #pragma unroll
            for (int r = 0; r < RB; ++r) xv[r] = xn[r];
            const int inext = (i + 1 < TT) ? (i + 1) : (TT - 1);
            #pragma unroll
            for (int r = 0; r < RB; ++r) xn[r] = x[(row0 + r) * TT + inext];

            #pragma unroll
            for (int r = 0; r < RB; ++r)
                #pragma unroll
                for (int g = 0; g < 4; ++g)
                    acc[r][g] = (ck == 0) ? __fmaf_rn(xv[r], wx[g], bg[g]) : 0.0f;

            const float* hb = &h0buf[pr][0][16 * ck];
            #pragma unroll
            for (int r = 0; r < RB; ++r) {
                const float4* hp = (const float4*)(hb + r * HD);
                #pragma unroll
                for (int k4 = 0; k4 < 4; ++k4) {
                    const float4 hv = hp[k4];
                    #pragma unroll
                    for (int g = 0; g < 4; ++g) {
                        acc[r][g] = __fmaf_rn(w[g][4*k4+0], hv.x, acc[r][g]);
                        acc[r][g] = __fmaf_rn(w[g][4*k4+1], hv.y, acc[r][g]);
                        acc[r][g] = __fmaf_rn(w[g][4*k4+2], hv.z, acc[r][g]);
                        acc[r][g] = __fmaf_rn(w[g][4*k4+3], hv.w, acc[r][g]);
                    }
                }
            }
            // butterfly over the 4 chunk-threads (lanes ^1, ^2)
            #pragma unroll
            for (int r = 0; r < RB; ++r)
                #pragma unroll
                for (int g = 0; g < 4; ++g) {
                    acc[r][g] += __shfl_xor(acc[r][g], 1, 64);
                    acc[r][g] += __shfl_xor(acc[r][g], 2, 64);
                }
            // elementwise: thread ck handles row r = ck
            {
                float e[4];
                #pragma unroll
                for (int g = 0; g < 4; ++g) {
                    float v = acc[0][g];
                    v = (ck == 1) ? acc[1][g] : v;
                    v = (ck == 2) ? acc[2][g] : v;
                    v = (ck == 3) ? acc[3][g] : v;
                    e[g] = v;
                }
                const float gi = fsig(e[0]);
                const float gf = fsig(e[1]);
                const float gg = ftanh_(e[2]);
                const float go = fsig(e[3]);
                cc = __fmaf_rn(gf, cc, gi * gg);
                h0buf[pw][ck][j] = go * ftanh_(cc);
            }
        } else {
            // -------- layer1, step i-1 --------
            #pragma unroll
            for (int r = 0; r < RB; ++r)
                #pragma unroll
                for (int g = 0; g < 4; ++g)
                    acc[r][g] = (ck == 0) ? bg[g] : 0.0f;

            const float* hb = (ck < 4) ? &h0buf[pr][0][16 * ck]
                                       : &h2buf[pw][0][16 * ck - HD];
            #pragma unroll
            for (int r = 0; r < RB; ++r) {
                const float4* hp = (const float4*)(hb + r * HD);
                #pragma unroll
                for (int k4 = 0; k4 < 4; ++k4) {
                    const float4 hv = hp[k4];
                    #pragma unroll
                    for (int g = 0; g < 4; ++g) {
                        acc[r][g] = __fmaf_rn(w[g][4*k4+0], hv.x, acc[r][g]);
                        acc[r][g] = __fmaf_rn(w[g][4*k4+1], hv.y, acc[r][g]);
                        acc[r][g] = __fmaf_rn(w[g][4*k4+2], hv.z, acc[r][g]);
                        acc[r][g] = __fmaf_rn(w[g][4*k4+3], hv.w, acc[r][g]);
                    }
                }
            }
            // butterfly over the 8 chunk-threads (lanes ^1, ^2, ^4)
            #pragma unroll
            for (int r = 0; r < RB; ++r)
                #pragma unroll
                for (int g = 0; g < 4; ++g) {
                    acc[r][g] += __shfl_xor(acc[r][g], 1, 64);
                    acc[r][g] += __shfl_xor(acc[r][g], 2, 64);
                    acc[r][g] += __shfl_xor(acc[r][g], 4, 64);
                }
            if (ck < 4 && i > 0) {
                float e[4];
                #pragma unroll
                for (int g = 0; g < 4; ++g) {
                    float v = acc[0][g];
                    v = (ck == 1) ? acc[1][g] : v;
                    v = (ck == 2) ? acc[2][g] : v;
                    v = (ck == 3) ? acc[3][g] : v;
                    e[g] = v;
                }
                const float gi = fsig(e[0]);
                const float gf = fsig(e[1]);
                const float gg = ftanh_(e[2]);
                const float go = fsig(e[3]);
                cc = __fmaf_rn(gf, cc, gi * gg);
                hlast = go * ftanh_(cc);
                h2buf[pr][ck][j] = hlast;
            }
        }
        __syncthreads();
    }

    // ---------------- FC: out[row] = sum_j h2[T-1][row][j]*fcW[j] + fcb ----------------
    if (!isL0 && ck < 4) fcs[ck * HD + j] = hlast * fcwj;
    __syncthreads();

    if (tid < 64) {
        const int r   = tid >> 4;
        const int seg = tid & 15;
        const float4 v = ((const float4*)fcs)[r * 16 + seg];
        float s = (v.x + v.y) + (v.z + v.w);
        s += __shfl_xor(s, 1, 64);
        s += __shfl_xor(s, 2, 64);
        s += __shfl_xor(s, 4, 64);
        s += __shfl_xor(s, 8, 64);
        if (seg == 0) out[row0 + r] = s + fcb[0];
    }
}

extern "C" void kernel_launch(void* const* d_in, const int* in_sizes, int n_in,
                              void* d_out, int out_size, void* d_ws, size_t ws_size,
                              hipStream_t stream) {
    const float* x    = (const float*)d_in[0];
    const float* Wih0 = (const float*)d_in[1];
    const float* Whh0 = (const float*)d_in[2];
    const float* bih0 = (const float*)d_in[3];
    const float* bhh0 = (const float*)d_in[4];
    const float* Wih1 = (const float*)d_in[5];
    const float* Whh1 = (const float*)d_in[6];
    const float* bih1 = (const float*)d_in[7];
    const float* bhh1 = (const float*)d_in[8];
    const float* fcW  = (const float*)d_in[9];
    const float* fcb  = (const float*)d_in[10];
    float* out = (float*)d_out;

    lstm2_kernel<<<256, 768, 0, stream>>>(x, Wih0, Whh0, bih0, bhh0,
                                          Wih1, Whh1, bih1, bhh1,
                                          fcW, fcb, out);
}

// Round 3
// 5189.028 us; speedup vs baseline: 1.1894x; 1.1894x over previous
//
#include <hip/hip_runtime.h>

#define TT 2048
#define HD 64

// LDS arena byte map:
//   h1 : [0, 2048)      parity p, row r at (p*4+r)*256 B; 16B blocks XOR-swizzled
//   h2 : [2112, 4160)   same layout, +64B skew so h1+h2 chunk reads cover all 32 banks
//   fcs: [4160, 5184)
#define H1_BASE 0
#define H2_BASE 2112
#define FCS_BASE 4160

__device__ __forceinline__ float fsig(float x)  { return 1.0f / (1.0f + __expf(-x)); }
__device__ __forceinline__ float ftanh_(float x){ return 1.0f - 2.0f / (1.0f + __expf(2.0f * x)); }

// 16B-block swizzle within a 256B row: block index b in [0,16) -> byte offset
__device__ __forceinline__ int swz(int b) { return ((b ^ ((b >> 2) & 3)) << 4); }

#define DOT16(acc, W0, W1, W2, W3) \
    acc = __fmaf_rn(W0.x, hv0.x, acc); acc = __fmaf_rn(W0.y, hv0.y, acc); \
    acc = __fmaf_rn(W0.z, hv0.z, acc); acc = __fmaf_rn(W0.w, hv0.w, acc); \
    acc = __fmaf_rn(W1.x, hv1.x, acc); acc = __fmaf_rn(W1.y, hv1.y, acc); \
    acc = __fmaf_rn(W1.z, hv1.z, acc); acc = __fmaf_rn(W1.w, hv1.w, acc); \
    acc = __fmaf_rn(W2.x, hv2.x, acc); acc = __fmaf_rn(W2.y, hv2.y, acc); \
    acc = __fmaf_rn(W2.z, hv2.z, acc); acc = __fmaf_rn(W2.w, hv2.w, acc); \
    acc = __fmaf_rn(W3.x, hv3.x, acc); acc = __fmaf_rn(W3.y, hv3.y, acc); \
    acc = __fmaf_rn(W3.z, hv3.z, acc); acc = __fmaf_rn(W3.w, hv3.w, acc);

#define ROWDOT(R, A0, A1, A2, A3) { \
    const float4 hv0 = *(const float4*)(rp + (R)*256 + o0); \
    const float4 hv1 = *(const float4*)(rp + (R)*256 + o1); \
    const float4 hv2 = *(const float4*)(rp + (R)*256 + o2); \
    const float4 hv3 = *(const float4*)(rp + (R)*256 + o3); \
    DOT16(A0, wA0, wA1, wA2, wA3); \
    DOT16(A1, wB0, wB1, wB2, wB3); \
    DOT16(A2, wC0, wC1, wC2, wC3); \
    DOT16(A3, wD0, wD1, wD2, wD3); }

#define BF2(v) { v += __shfl_xor(v, 1, 64); v += __shfl_xor(v, 2, 64); }
#define BF4(v) { v += __shfl_xor(v, 4, 64); }

// pick row=ck value out of the 4 row-accumulators (all lanes hold full sums)
#define SEL4(e, x0, x1, x2, x3) \
    float e = x0; e = (ck == 1) ? x1 : e; e = (ck == 2) ? x2 : e; e = (ck == 3) ? x3 : e;

// Block = 768 threads, 4 batch rows per block.
//   waves 0-3  (tid 0..255):   layer0.  j=tid>>2 (unit), ck=tid&3  (16-wide K chunk of 64)
//   waves 4-11 (tid 256..767): layer1.  p=tid-256, j=p>>3, ck=p&7 (16-wide chunk of K=128=[h1|h2])
// Pipeline: iter i does layer0 step i and layer1 step i-1; ONE barrier per iter.
__global__ __launch_bounds__(768, 3)
void lstm2_kernel(const float* __restrict__ x,
                  const float* __restrict__ Wih0,
                  const float* __restrict__ Whh0,
                  const float* __restrict__ bih0,
                  const float* __restrict__ bhh0,
                  const float* __restrict__ Wih1,
                  const float* __restrict__ Whh1,
                  const float* __restrict__ bih1,
                  const float* __restrict__ bhh1,
                  const float* __restrict__ fcW,
                  const float* __restrict__ fcb,
                  float* __restrict__ out)
{
    __shared__ __align__(16) float arena_f[1296];
    char* const arena = (char*)arena_f;

    const int tid  = threadIdx.x;
    const int row0 = blockIdx.x * 4;

    const bool isL0 = (tid < 256);
    const int  p    = isL0 ? tid : (tid - 256);
    const int  j    = isL0 ? (p >> 2) : (p >> 3);
    const int  ck   = isL0 ? (p & 3)  : (p & 7);
    const int  ckk  = (ck < 4) ? ck : (ck - 4);

    // ---- weights: 16 explicit float4 registers (64 VGPRs), no arrays ----
    const float* Wsrc;
    if (isL0)        Wsrc = Whh0;
    else if (ck < 4) Wsrc = Wih1;
    else             Wsrc = Whh1;
    const int kbase = 16 * ckk;
    const float4* W0p = (const float4*)(Wsrc + (0 * HD + j) * HD + kbase);
    const float4* W1p = (const float4*)(Wsrc + (1 * HD + j) * HD + kbase);
    const float4* W2p = (const float4*)(Wsrc + (2 * HD + j) * HD + kbase);
    const float4* W3p = (const float4*)(Wsrc + (3 * HD + j) * HD + kbase);
    const float4 wA0 = W0p[0], wA1 = W0p[1], wA2 = W0p[2], wA3 = W0p[3];
    const float4 wB0 = W1p[0], wB1 = W1p[1], wB2 = W1p[2], wB3 = W1p[3];
    const float4 wC0 = W2p[0], wC1 = W2p[1], wC2 = W2p[2], wC3 = W2p[3];
    const float4 wD0 = W3p[0], wD1 = W3p[1], wD2 = W3p[2], wD3 = W3p[3];

    // masked bias / x-weight (only chunk 0 injects them)
    float bgm0, bgm1, bgm2, bgm3, wxm0 = 0.f, wxm1 = 0.f, wxm2 = 0.f, wxm3 = 0.f;
    {
        const bool cz = (ck == 0);
        if (isL0) {
            bgm0 = cz ? (bih0[0*HD+j] + bhh0[0*HD+j]) : 0.f;
            bgm1 = cz ? (bih0[1*HD+j] + bhh0[1*HD+j]) : 0.f;
            bgm2 = cz ? (bih0[2*HD+j] + bhh0[2*HD+j]) : 0.f;
            bgm3 = cz ? (bih0[3*HD+j] + bhh0[3*HD+j]) : 0.f;
            wxm0 = cz ? Wih0[0*HD+j] : 0.f;
            wxm1 = cz ? Wih0[1*HD+j] : 0.f;
            wxm2 = cz ? Wih0[2*HD+j] : 0.f;
            wxm3 = cz ? Wih0[3*HD+j] : 0.f;
        } else {
            bgm0 = cz ? (bih1[0*HD+j] + bhh1[0*HD+j]) : 0.f;
            bgm1 = cz ? (bih1[1*HD+j] + bhh1[1*HD+j]) : 0.f;
            bgm2 = cz ? (bih1[2*HD+j] + bhh1[2*HD+j]) : 0.f;
            bgm3 = cz ? (bih1[3*HD+j] + bhh1[3*HD+j]) : 0.f;
        }
    }

    // per-thread LDS read constants: swizzled block offsets + buffer/parity phase
    const int o0 = swz(4 * ckk + 0);
    const int o1 = swz(4 * ckk + 1);
    const int o2 = swz(4 * ckk + 2);
    const int o3 = swz(4 * ckk + 3);
    const int rdBufBase = (ck < 4) ? H1_BASE : H2_BASE;   // isL0 has ck<4
    const int rdPhase   = (ck < 4) ? 1 : 0;               // h1 readers: (i+1)&1; h2: i&1

    // zero both parities of h1 and h2 (swizzle is a bijection -> linear zero OK)
    for (int z = tid; z < 512; z += 768) {
        *(float*)(arena + H1_BASE + 4 * z) = 0.f;
        *(float*)(arena + H2_BASE + 4 * z) = 0.f;
    }

    const float* xp0 = x + (row0 + 0) * TT;
    const float* xp1 = x + (row0 + 1) * TT;
    const float* xp2 = x + (row0 + 2) * TT;
    const float* xp3 = x + (row0 + 3) * TT;
    float xn0 = 0.f, xn1 = 0.f, xn2 = 0.f, xn3 = 0.f;
    if (isL0) { xn0 = xp0[0]; xn1 = xp1[0]; xn2 = xp2[0]; xn3 = xp3[0]; }

    const float fcwj = fcW[j];
    float cc = 0.f, hlast = 0.f;

    __syncthreads();

    for (int i = 0; i <= TT; ++i) {
        const char* rp = arena + rdBufBase + (((i + rdPhase) & 1) << 10);

        float a00, a01, a02, a03, a10, a11, a12, a13;
        float a20, a21, a22, a23, a30, a31, a32, a33;

        if (isL0) {
            const float xv0 = xn0, xv1 = xn1, xv2 = xn2, xv3 = xn3;
            const int inext = (i + 1 < TT) ? (i + 1) : (TT - 1);
            xn0 = xp0[inext]; xn1 = xp1[inext]; xn2 = xp2[inext]; xn3 = xp3[inext];
            a00 = __fmaf_rn(xv0, wxm0, bgm0); a01 = __fmaf_rn(xv0, wxm1, bgm1);
            a02 = __fmaf_rn(xv0, wxm2, bgm2); a03 = __fmaf_rn(xv0, wxm3, bgm3);
            a10 = __fmaf_rn(xv1, wxm0, bgm0); a11 = __fmaf_rn(xv1, wxm1, bgm1);
            a12 = __fmaf_rn(xv1, wxm2, bgm2); a13 = __fmaf_rn(xv1, wxm3, bgm3);
            a20 = __fmaf_rn(xv2, wxm0, bgm0); a21 = __fmaf_rn(xv2, wxm1, bgm1);
            a22 = __fmaf_rn(xv2, wxm2, bgm2); a23 = __fmaf_rn(xv2, wxm3, bgm3);
            a30 = __fmaf_rn(xv3, wxm0, bgm0); a31 = __fmaf_rn(xv3, wxm1, bgm1);
            a32 = __fmaf_rn(xv3, wxm2, bgm2); a33 = __fmaf_rn(xv3, wxm3, bgm3);
        } else {
            a00 = bgm0; a01 = bgm1; a02 = bgm2; a03 = bgm3;
            a10 = bgm0; a11 = bgm1; a12 = bgm2; a13 = bgm3;
            a20 = bgm0; a21 = bgm1; a22 = bgm2; a23 = bgm3;
            a30 = bgm0; a31 = bgm1; a32 = bgm2; a33 = bgm3;
        }

        ROWDOT(0, a00, a01, a02, a03)
        ROWDOT(1, a10, a11, a12, a13)
        ROWDOT(2, a20, a21, a22, a23)
        ROWDOT(3, a30, a31, a32, a33)

        BF2(a00) BF2(a01) BF2(a02) BF2(a03)
        BF2(a10) BF2(a11) BF2(a12) BF2(a13)
        BF2(a20) BF2(a21) BF2(a22) BF2(a23)
        BF2(a30) BF2(a31) BF2(a32) BF2(a33)
        if (!isL0) {
            BF4(a00) BF4(a01) BF4(a02) BF4(a03)
            BF4(a10) BF4(a11) BF4(a12) BF4(a13)
            BF4(a20) BF4(a21) BF4(a22) BF4(a23)
            BF4(a30) BF4(a31) BF4(a32) BF4(a33)
        }

        if (isL0) {
            // every layer0 thread finalizes (row=ck, unit=j)
            SEL4(e0, a00, a10, a20, a30)
            SEL4(e1, a01, a11, a21, a31)
            SEL4(e2, a02, a12, a22, a32)
            SEL4(e3, a03, a13, a23, a33)
            const float iv = fsig(e0), fv = fsig(e1), gv = ftanh_(e2), ov = fsig(e3);
            cc = __fmaf_rn(fv, cc, iv * gv);
            const float hh = ov * ftanh_(cc);
            // h1[i] at parity i&1
            *(float*)(arena + H1_BASE + ((i & 1) << 10) + (ck << 8)
                      + swz(j >> 2) + ((j & 3) << 2)) = hh;
        } else if (ck < 4) {
            if (i > 0) {
                SEL4(e0, a00, a10, a20, a30)
                SEL4(e1, a01, a11, a21, a31)
                SEL4(e2, a02, a12, a22, a32)
                SEL4(e3, a03, a13, a23, a33)
                const float iv = fsig(e0), fv = fsig(e1), gv = ftanh_(e2), ov = fsig(e3);
                cc = __fmaf_rn(fv, cc, iv * gv);
                hlast = ov * ftanh_(cc);
                // h2[i-1] at parity (i+1)&1
                *(float*)(arena + H2_BASE + (((i + 1) & 1) << 10) + (ck << 8)
                          + swz(j >> 2) + ((j & 3) << 2)) = hlast;
            }
        }
        __syncthreads();
    }

    // ---- FC: out[row] = sum_j h2[T-1][row][j] * fcW[j] + fcb ----
    if (!isL0 && ck < 4)
        *(float*)(arena + FCS_BASE + ((ck * HD + j) << 2)) = hlast * fcwj;
    __syncthreads();

    if (tid < 64) {
        const int r = tid >> 4, seg = tid & 15;
        const float4 v = ((const float4*)(arena + FCS_BASE))[r * 16 + seg];
        float s = (v.x + v.y) + (v.z + v.w);
        s += __shfl_xor(s, 1, 64);
        s += __shfl_xor(s, 2, 64);
        s += __shfl_xor(s, 4, 64);
        s += __shfl_xor(s, 8, 64);
        if (seg == 0) out[row0 + r] = s + fcb[0];
    }
}

extern "C" void kernel_launch(void* const* d_in, const int* in_sizes, int n_in,
                              void* d_out, int out_size, void* d_ws, size_t ws_size,
                              hipStream_t stream) {
    const float* x    = (const float*)d_in[0];
    const float* Wih0 = (const float*)d_in[1];
    const float* Whh0 = (const float*)d_in[2];
    const float* bih0 = (const float*)d_in[3];
    const float* bhh0 = (const float*)d_in[4];
    const float* Wih1 = (const float*)d_in[5];
    const float* Whh1 = (const float*)d_in[6];
    const float* bih1 = (const float*)d_in[7];
    const float* bhh1 = (const float*)d_in[8];
    const float* fcW  = (const float*)d_in[9];
    const float* fcb  = (const float*)d_in[10];
    float* out = (float*)d_out;

    lstm2_kernel<<<256, 768, 0, stream>>>(x, Wih0, Whh0, bih0, bhh0,
                                          Wih1, Whh1, bih1, bhh1,
                                          fcW, fcb, out);
}

// Round 4
// 4061.502 us; speedup vs baseline: 1.5196x; 1.2776x over previous
//
#include <hip/hip_runtime.h>

#define TT 2048
#define HD 64

// LDS arena byte map:
//   h1 : [0, 2048)      parity p, row r at (p*4+r)*256 B; 16B blocks XOR-swizzled
//   h2 : [2112, 4160)   same layout, +64B skew so h1+h2 chunk reads cover all 32 banks
//   fcs: [4160, 5184)
#define H1_BASE 0
#define H2_BASE 2112
#define FCS_BASE 4160

__device__ __forceinline__ float fsig(float x)  { return 1.0f / (1.0f + __expf(-x)); }
__device__ __forceinline__ float ftanh_(float x){ return 1.0f - 2.0f / (1.0f + __expf(2.0f * x)); }

// 16B-block swizzle within a 256B row: block index b in [0,16) -> byte offset
__device__ __forceinline__ int swz(int b) { return ((b ^ ((b >> 2) & 3)) << 4); }

// DPP quad_perm add: pure VALU cross-lane, stays OFF the LDS pipe.
// 0xB1 = quad_perm[1,0,3,2] (xor 1), 0x4E = quad_perm[2,3,0,1] (xor 2).
template<int CTRL>
__device__ __forceinline__ float dpp_add(float v) {
    const int o = __builtin_amdgcn_update_dpp(0, __float_as_int(v), CTRL, 0xF, 0xF, true);
    return v + __int_as_float(o);
}
#define BF2D(v) { v = dpp_add<0xB1>(v); v = dpp_add<0x4E>(v); }

#define DOT16(acc, W0, W1, W2, W3) \
    acc = __fmaf_rn(W0.x, hv0.x, acc); acc = __fmaf_rn(W0.y, hv0.y, acc); \
    acc = __fmaf_rn(W0.z, hv0.z, acc); acc = __fmaf_rn(W0.w, hv0.w, acc); \
    acc = __fmaf_rn(W1.x, hv1.x, acc); acc = __fmaf_rn(W1.y, hv1.y, acc); \
    acc = __fmaf_rn(W1.z, hv1.z, acc); acc = __fmaf_rn(W1.w, hv1.w, acc); \
    acc = __fmaf_rn(W2.x, hv2.x, acc); acc = __fmaf_rn(W2.y, hv2.y, acc); \
    acc = __fmaf_rn(W2.z, hv2.z, acc); acc = __fmaf_rn(W2.w, hv2.w, acc); \
    acc = __fmaf_rn(W3.x, hv3.x, acc); acc = __fmaf_rn(W3.y, hv3.y, acc); \
    acc = __fmaf_rn(W3.z, hv3.z, acc); acc = __fmaf_rn(W3.w, hv3.w, acc);

#define ROWDOT(R, A0, A1, A2, A3) { \
    const float4 hv0 = *(const float4*)(rp + (R)*256 + o0); \
    const float4 hv1 = *(const float4*)(rp + (R)*256 + o1); \
    const float4 hv2 = *(const float4*)(rp + (R)*256 + o2); \
    const float4 hv3 = *(const float4*)(rp + (R)*256 + o3); \
    DOT16(A0, wA0, wA1, wA2, wA3); \
    DOT16(A1, wB0, wB1, wB2, wB3); \
    DOT16(A2, wC0, wC1, wC2, wC3); \
    DOT16(A3, wD0, wD1, wD2, wD3); }

// pick row=rk value out of the 4 row-accumulators (all lanes hold quad/full sums)
#define SEL4(e, x0, x1, x2, x3) \
    float e = x0; e = (rk == 1) ? x1 : e; e = (rk == 2) ? x2 : e; e = (rk == 3) ? x3 : e;

// Block = 768 threads, 4 batch rows per block.
//   waves 0-3  (tid 0..255):   layer0.  j=tid>>2 (unit), ck=tid&3  (16-wide K chunk of 64)
//   waves 4-11 (tid 256..767): layer1.  p=tid-256, j=p>>3, ck=p&7 (16-wide chunk of K=128=[h1|h2])
// Reduction: xor1+xor2 via DPP quad_perm (VALU); L1's xor4 via 4 ds_swizzle AFTER row-select.
// Pipeline: iter i does layer0 step i and layer1 step i-1; ONE barrier per iter.
__global__ __launch_bounds__(768, 3)
void lstm2_kernel(const float* __restrict__ x,
                  const float* __restrict__ Wih0,
                  const float* __restrict__ Whh0,
                  const float* __restrict__ bih0,
                  const float* __restrict__ bhh0,
                  const float* __restrict__ Wih1,
                  const float* __restrict__ Whh1,
                  const float* __restrict__ bih1,
                  const float* __restrict__ bhh1,
                  const float* __restrict__ fcW,
                  const float* __restrict__ fcb,
                  float* __restrict__ out)
{
    __shared__ __align__(16) float arena_f[1296];
    char* const arena = (char*)arena_f;

    const int tid  = threadIdx.x;
    const int row0 = blockIdx.x * 4;

    const bool isL0 = (tid < 256);
    const int  p    = isL0 ? tid : (tid - 256);
    const int  j    = isL0 ? (p >> 2) : (p >> 3);
    const int  ck   = isL0 ? (p & 3)  : (p & 7);
    const int  ckk  = (ck < 4) ? ck : (ck - 4);
    const int  rk   = ck & 3;                      // this lane's output row

    // ---- weights: 16 explicit float4 registers (64 VGPRs), no arrays ----
    const float* Wsrc;
    if (isL0)        Wsrc = Whh0;
    else if (ck < 4) Wsrc = Wih1;
    else             Wsrc = Whh1;
    const int kbase = 16 * ckk;
    const float4* W0p = (const float4*)(Wsrc + (0 * HD + j) * HD + kbase);
    const float4* W1p = (const float4*)(Wsrc + (1 * HD + j) * HD + kbase);
    const float4* W2p = (const float4*)(Wsrc + (2 * HD + j) * HD + kbase);
    const float4* W3p = (const float4*)(Wsrc + (3 * HD + j) * HD + kbase);
    const float4 wA0 = W0p[0], wA1 = W0p[1], wA2 = W0p[2], wA3 = W0p[3];
    const float4 wB0 = W1p[0], wB1 = W1p[1], wB2 = W1p[2], wB3 = W1p[3];
    const float4 wC0 = W2p[0], wC1 = W2p[1], wC2 = W2p[2], wC3 = W2p[3];
    const float4 wD0 = W3p[0], wD1 = W3p[1], wD2 = W3p[2], wD3 = W3p[3];

    // masked bias / x-weight (only chunk 0 injects them)
    float bgm0, bgm1, bgm2, bgm3, wxm0 = 0.f, wxm1 = 0.f, wxm2 = 0.f, wxm3 = 0.f;
    {
        const bool cz = (ck == 0);
        if (isL0) {
            bgm0 = cz ? (bih0[0*HD+j] + bhh0[0*HD+j]) : 0.f;
            bgm1 = cz ? (bih0[1*HD+j] + bhh0[1*HD+j]) : 0.f;
            bgm2 = cz ? (bih0[2*HD+j] + bhh0[2*HD+j]) : 0.f;
            bgm3 = cz ? (bih0[3*HD+j] + bhh0[3*HD+j]) : 0.f;
            wxm0 = cz ? Wih0[0*HD+j] : 0.f;
            wxm1 = cz ? Wih0[1*HD+j] : 0.f;
            wxm2 = cz ? Wih0[2*HD+j] : 0.f;
            wxm3 = cz ? Wih0[3*HD+j] : 0.f;
        } else {
            bgm0 = cz ? (bih1[0*HD+j] + bhh1[0*HD+j]) : 0.f;
            bgm1 = cz ? (bih1[1*HD+j] + bhh1[1*HD+j]) : 0.f;
            bgm2 = cz ? (bih1[2*HD+j] + bhh1[2*HD+j]) : 0.f;
            bgm3 = cz ? (bih1[3*HD+j] + bhh1[3*HD+j]) : 0.f;
        }
    }

    // per-thread LDS read constants: swizzled block offsets + buffer/parity phase
    const int o0 = swz(4 * ckk + 0);
    const int o1 = swz(4 * ckk + 1);
    const int o2 = swz(4 * ckk + 2);
    const int o3 = swz(4 * ckk + 3);
    const int rdBufBase = (ck < 4) ? H1_BASE : H2_BASE;   // isL0 has ck<4
    const int rdPhase   = (ck < 4) ? 1 : 0;               // h1 readers: (i+1)&1; h2: i&1

    // zero both parities of h1 and h2 (swizzle is a bijection -> linear zero OK)
    for (int z = tid; z < 512; z += 768) {
        *(float*)(arena + H1_BASE + 4 * z) = 0.f;
        *(float*)(arena + H2_BASE + 4 * z) = 0.f;
    }

    const float* xp0 = x + (row0 + 0) * TT;
    const float* xp1 = x + (row0 + 1) * TT;
    const float* xp2 = x + (row0 + 2) * TT;
    const float* xp3 = x + (row0 + 3) * TT;
    float xn0 = 0.f, xn1 = 0.f, xn2 = 0.f, xn3 = 0.f;
    if (isL0) { xn0 = xp0[0]; xn1 = xp1[0]; xn2 = xp2[0]; xn3 = xp3[0]; }

    const float fcwj = fcW[j];
    float cc = 0.f, hlast = 0.f;

    __syncthreads();

    for (int i = 0; i <= TT; ++i) {
        const char* rp = arena + rdBufBase + (((i + rdPhase) & 1) << 10);

        float a00, a01, a02, a03, a10, a11, a12, a13;
        float a20, a21, a22, a23, a30, a31, a32, a33;

        if (isL0) {
            const float xv0 = xn0, xv1 = xn1, xv2 = xn2, xv3 = xn3;
            const int inext = (i + 1 < TT) ? (i + 1) : (TT - 1);
            xn0 = xp0[inext]; xn1 = xp1[inext]; xn2 = xp2[inext]; xn3 = xp3[inext];
            a00 = __fmaf_rn(xv0, wxm0, bgm0); a01 = __fmaf_rn(xv0, wxm1, bgm1);
            a02 = __fmaf_rn(xv0, wxm2, bgm2); a03 = __fmaf_rn(xv0, wxm3, bgm3);
            a10 = __fmaf_rn(xv1, wxm0, bgm0); a11 = __fmaf_rn(xv1, wxm1, bgm1);
            a12 = __fmaf_rn(xv1, wxm2, bgm2); a13 = __fmaf_rn(xv1, wxm3, bgm3);
            a20 = __fmaf_rn(xv2, wxm0, bgm0); a21 = __fmaf_rn(xv2, wxm1, bgm1);
            a22 = __fmaf_rn(xv2, wxm2, bgm2); a23 = __fmaf_rn(xv2, wxm3, bgm3);
            a30 = __fmaf_rn(xv3, wxm0, bgm0); a31 = __fmaf_rn(xv3, wxm1, bgm1);
            a32 = __fmaf_rn(xv3, wxm2, bgm2); a33 = __fmaf_rn(xv3, wxm3, bgm3);
        } else {
            a00 = bgm0; a01 = bgm1; a02 = bgm2; a03 = bgm3;
            a10 = bgm0; a11 = bgm1; a12 = bgm2; a13 = bgm3;
            a20 = bgm0; a21 = bgm1; a22 = bgm2; a23 = bgm3;
            a30 = bgm0; a31 = bgm1; a32 = bgm2; a33 = bgm3;
        }

        ROWDOT(0, a00, a01, a02, a03)
        ROWDOT(1, a10, a11, a12, a13)
        ROWDOT(2, a20, a21, a22, a23)
        ROWDOT(3, a30, a31, a32, a33)

        // intra-quad reduction (xor1 + xor2) on the VALU via DPP quad_perm
        BF2D(a00) BF2D(a01) BF2D(a02) BF2D(a03)
        BF2D(a10) BF2D(a11) BF2D(a12) BF2D(a13)
        BF2D(a20) BF2D(a21) BF2D(a22) BF2D(a23)
        BF2D(a30) BF2D(a31) BF2D(a32) BF2D(a33)

        // select this lane's row FIRST (16 -> 4 values)...
        SEL4(e0, a00, a10, a20, a30)
        SEL4(e1, a01, a11, a21, a31)
        SEL4(e2, a02, a12, a22, a32)
        SEL4(e3, a03, a13, a23, a33)

        // ...then L1's cross-quad combine is only 4 swizzles (quad0 = h1-half, quad1 = h2-half)
        if (!isL0) {
            e0 += __shfl_xor(e0, 4, 64);
            e1 += __shfl_xor(e1, 4, 64);
            e2 += __shfl_xor(e2, 4, 64);
            e3 += __shfl_xor(e3, 4, 64);
        }

        if (isL0) {
            const float iv = fsig(e0), fv = fsig(e1), gv = ftanh_(e2), ov = fsig(e3);
            cc = __fmaf_rn(fv, cc, iv * gv);
            const float hh = ov * ftanh_(cc);
            // h1[i] at parity i&1  (row = ck, unit = j)
            *(float*)(arena + H1_BASE + ((i & 1) << 10) + (ck << 8)
                      + swz(j >> 2) + ((j & 3) << 2)) = hh;
        } else if (ck < 4 && i > 0) {
            const float iv = fsig(e0), fv = fsig(e1), gv = ftanh_(e2), ov = fsig(e3);
            cc = __fmaf_rn(fv, cc, iv * gv);
            hlast = ov * ftanh_(cc);
            // h2[i-1] at parity (i+1)&1
            *(float*)(arena + H2_BASE + (((i + 1) & 1) << 10) + (ck << 8)
                      + swz(j >> 2) + ((j & 3) << 2)) = hlast;
        }
        __syncthreads();
    }

    // ---- FC: out[row] = sum_j h2[T-1][row][j] * fcW[j] + fcb ----
    if (!isL0 && ck < 4)
        *(float*)(arena + FCS_BASE + ((ck * HD + j) << 2)) = hlast * fcwj;
    __syncthreads();

    if (tid < 64) {
        const int r = tid >> 4, seg = tid & 15;
        const float4 v = ((const float4*)(arena + FCS_BASE))[r * 16 + seg];
        float s = (v.x + v.y) + (v.z + v.w);
        s += __shfl_xor(s, 1, 64);
        s += __shfl_xor(s, 2, 64);
        s += __shfl_xor(s, 4, 64);
        s += __shfl_xor(s, 8, 64);
        if (seg == 0) out[row0 + r] = s + fcb[0];
    }
}

extern "C" void kernel_launch(void* const* d_in, const int* in_sizes, int n_in,
                              void* d_out, int out_size, void* d_ws, size_t ws_size,
                              hipStream_t stream) {
    const float* x    = (const float*)d_in[0];
    const float* Wih0 = (const float*)d_in[1];
    const float* Whh0 = (const float*)d_in[2];
    const float* bih0 = (const float*)d_in[3];
    const float* bhh0 = (const float*)d_in[4];
    const float* Wih1 = (const float*)d_in[5];
    const float* Whh1 = (const float*)d_in[6];
    const float* bih1 = (const float*)d_in[7];
    const float* bhh1 = (const float*)d_in[8];
    const float* fcW  = (const float*)d_in[9];
    const float* fcb  = (const float*)d_in[10];
    float* out = (float*)d_out;

    lstm2_kernel<<<256, 768, 0, stream>>>(x, Wih0, Whh0, bih0, bhh0,
                                          Wih1, Whh1, bih1, bhh1,
                                          fcW, fcb, out);
}